// Round 4
// baseline (712.614 us; speedup 1.0000x reference)
//
#include <hip/hip_runtime.h>
#include <math.h>

#define NB 32
#define NC 512
#define HW 4096
#define NSEG 128
#define NCLS 19

// ws layout (bytes):
//   sums   [32][128][512] f32 : off 0        size 8388608
//   counts [32][128]      f32 : off 8388608  size 16384
//   alog   [32][128]      f32 : off 8404992  size 16384
//   wloss  [32]           f32 : off 8421376  size 128
//   ids    [32][4096]     u8  : off 8421504  size 131072
#define OFF_COUNTS 8388608
#define OFF_ALOG   8404992
#define OFF_WLOSS  8421376
#define OFF_IDS    8421504
#define ZERO_F4    525312   // (sums+counts) bytes / 16 == 513*1024 exactly

// ---------------------------------------------------------------------------
// K0: zero sums + counts
// ---------------------------------------------------------------------------
__global__ __launch_bounds__(256) void k_zero(float4* __restrict__ p) {
  int i = blockIdx.x * 1024 + threadIdx.x;
  float4 z = make_float4(0.f, 0.f, 0.f, 0.f);
#pragma unroll
  for (int j = 0; j < 4; ++j) p[i + j * 256] = z;
}

// ---------------------------------------------------------------------------
// K1: downsample mask -> ids (u8) + per-segment counts
// ---------------------------------------------------------------------------
__global__ __launch_bounds__(256) void k_ids_counts(const int* __restrict__ mask,
                                                    unsigned char* __restrict__ ids,
                                                    float* __restrict__ counts) {
  int rq = blockIdx.x, b = blockIdx.y;
  int t = threadIdx.x;
  __shared__ int cnt[NSEG + 1];
  if (t < NSEG + 1) cnt[t] = 0;
  __syncthreads();
  const int* mb = mask + (size_t)b * 262144;
  int p0 = rq * 1024 + t * 4;
  uchar4 wv;
  unsigned char* wp = (unsigned char*)&wv;
#pragma unroll
  for (int j = 0; j < 4; ++j) {
    int p = p0 + j;
    int i = p >> 6, jj = p & 63;
    int id = mb[i * 4096 + jj * 8];
    wp[j] = (unsigned char)id;
    atomicAdd(&cnt[id], 1);
  }
  *(uchar4*)(ids + (size_t)b * HW + p0) = wv;
  __syncthreads();
  if (t < NSEG) atomicAdd(&counts[b * NSEG + t], (float)cnt[t + 1]);
}

// ---------------------------------------------------------------------------
// K2: segment sums. grid (8 cc, 4 pq, 32 b). Per block: 64 ch x 1024 px.
// Per 64-px tile: stage x[64px][64ch] in LDS (coalesced), then scatter with
// lanes=channels: wave w owns pixels [16w,16w+16); per pixel, 64 lanes issue
// ds_add_f32 bins[s*65+lane] -- s wave-uniform => banks (s+lane)%32 two
// lanes/bank (free), no same-address collision, NO return => no dep chain.
// ---------------------------------------------------------------------------
__global__ __launch_bounds__(256) void k_segmeans(const float* __restrict__ x,
                                                  const unsigned char* __restrict__ ids,
                                                  float* __restrict__ sums) {
  int cc = blockIdx.x, pq = blockIdx.y, b = blockIdx.z;
  int t = threadIdx.x;
  int w = t >> 6;       // wave id -> pixel sub-range in scatter
  int lane = t & 63;    // scatter: channel lane
  __shared__ float bins[129 * 65];   // [seg][ch], row 0 = id-0 sink
  __shared__ float tile[64 * 65];    // [p_local][ch], stride 65
  __shared__ unsigned char lids[1024];

  for (int i = t; i < 129 * 65; i += 256) bins[i] = 0.f;
  ((uchar4*)lids)[t] = ((const uchar4*)(ids + (size_t)b * HW + pq * 1024))[t];

  int l16 = t & 15;     // staging: pixel sub-group (4 px each)
  int r0 = t >> 4;      // staging: channel row base
  const float* xbase = x + ((size_t)(b * NC + cc * 64)) * HW + pq * 1024 + 4 * l16;

  float4 v[4], vn[4];
#pragma unroll
  for (int rr = 0; rr < 4; ++rr)
    v[rr] = *(const float4*)(xbase + (size_t)(r0 + rr * 16) * HW);
  __syncthreads();

  for (int ti = 0; ti < 16; ++ti) {
    // stage current tile: tile[p*65 + c]
#pragma unroll
    for (int rr = 0; rr < 4; ++rr) {
      int c = r0 + rr * 16;
      int p = 4 * l16;
      tile[(p + 0) * 65 + c] = v[rr].x;
      tile[(p + 1) * 65 + c] = v[rr].y;
      tile[(p + 2) * 65 + c] = v[rr].z;
      tile[(p + 3) * 65 + c] = v[rr].w;
    }
    __syncthreads();
    // prefetch next tile's global loads (overlap with scatter)
    if (ti < 15) {
#pragma unroll
      for (int rr = 0; rr < 4; ++rr)
        vn[rr] = *(const float4*)(xbase + (size_t)(r0 + rr * 16) * HW + (ti + 1) * 64);
    }
    // scatter: wave w handles 16 pixels, fire-and-forget LDS atomics
    int pbase = ti * 64 + w * 16;
#pragma unroll 4
    for (int jj = 0; jj < 16; ++jj) {
      int s = lids[pbase + jj];
      atomicAdd(&bins[s * 65 + lane], tile[(w * 16 + jj) * 65 + lane]);
    }
    __syncthreads();
#pragma unroll
    for (int rr = 0; rr < 4; ++rr) v[rr] = vn[rr];
  }

  // flush partials (4 pq-blocks contend per sums element); skip id-0 sink row
  for (int i = t; i < NSEG * 64; i += 256) {
    int s = (i >> 6) + 1, c = i & 63;
    float vv = bins[s * 65 + c];
    if (vv != 0.f) atomicAdd(&sums[((size_t)b * NSEG + (s - 1)) * NC + cc * 64 + c], vv);
  }
}

// ---------------------------------------------------------------------------
// K3: attention logits. grid (16 s-tiles of 8, 32 b), 512 threads (8 waves).
// Thread t owns Wa1 column t; register prefetch of next k-quad.
// ---------------------------------------------------------------------------
__global__ __launch_bounds__(512) void k_att(const float* __restrict__ sums,
                                             const float* __restrict__ counts,
                                             const float* __restrict__ Wa1,
                                             const float* __restrict__ ba1,
                                             const float* __restrict__ Wa2,
                                             const float* __restrict__ ba2,
                                             float* __restrict__ alog) {
  int st = blockIdx.x, b = blockIdx.y;
  int t = threadIdx.x;
  __shared__ float mt[8 * 512];
  __shared__ float red[8][8];
  const float4* m4 = (const float4*)(sums + ((size_t)b * NSEG + st * 8) * NC);
  float4* mt4 = (float4*)mt;
#pragma unroll
  for (int i = 0; i < 2; ++i) {
    int idx = i * 512 + t;
    int r = idx >> 7;
    float cn = counts[b * NSEG + st * 8 + r];
    float inv = cn > 0.f ? 1.f / cn : 0.f;
    float4 mv = m4[idx];
    mv.x *= inv; mv.y *= inv; mv.z *= inv; mv.w *= inv;
    mt4[idx] = mv;
  }
  __syncthreads();

  float acc[8];
#pragma unroll
  for (int r = 0; r < 8; ++r) acc[r] = 0.f;

  float wc[4], wn[4];
#pragma unroll
  for (int kk = 0; kk < 4; ++kk) wc[kk] = Wa1[(size_t)kk * 512 + t];

  for (int k4 = 0; k4 < 128; ++k4) {
    if (k4 < 127) {
      int k = (k4 + 1) * 4;
#pragma unroll
      for (int kk = 0; kk < 4; ++kk) wn[kk] = Wa1[(size_t)(k + kk) * 512 + t];
    }
    int k = k4 * 4;
#pragma unroll
    for (int r = 0; r < 8; ++r) {
      float4 m = *(const float4*)&mt[r * 512 + k];
      acc[r] = fmaf(m.x, wc[0], fmaf(m.y, wc[1], fmaf(m.z, wc[2], fmaf(m.w, wc[3], acc[r]))));
    }
#pragma unroll
    for (int kk = 0; kk < 4; ++kk) wc[kk] = wn[kk];
  }

  float b1 = ba1[t];
  float w2 = Wa2[t];
  int lane = t & 63, wid = t >> 6;
#pragma unroll
  for (int r = 0; r < 8; ++r) {
    float v = fmaxf(acc[r] + b1, 0.f) * w2;
#pragma unroll
    for (int off = 32; off > 0; off >>= 1) v += __shfl_down(v, off, 64);
    if (lane == 0) red[wid][r] = v;
  }
  __syncthreads();
  if (t < 8) {
    float s = ba2[0];
#pragma unroll
    for (int g = 0; g < 8; ++g) s += red[g][t];
    alog[b * NSEG + st * 8 + t] = s;
  }
}

// ---------------------------------------------------------------------------
// K4: softmax -> weighted mean -> logits -> loss partial
// ---------------------------------------------------------------------------
__global__ __launch_bounds__(256) void k_head(const float* __restrict__ sums,
                                              const float* __restrict__ counts,
                                              const float* __restrict__ alog,
                                              const float* __restrict__ Wh,
                                              const float* __restrict__ bh,
                                              const float* __restrict__ target,
                                              float* __restrict__ out,
                                              float* __restrict__ wloss) {
  int b = blockIdx.x, t = threadIdx.x;
  __shared__ float att[NSEG];
  __shared__ float wm[NC];
  __shared__ float sred[4];
  __shared__ float sval;
  __shared__ float part[8][20];
  __shared__ float lg[NCLS];
  int lane = t & 63, wid = t >> 6;

  float l = (t < NSEG) ? alog[b * NSEG + t] : -INFINITY;
  float v = l;
#pragma unroll
  for (int off = 32; off > 0; off >>= 1) v = fmaxf(v, __shfl_down(v, off, 64));
  if (lane == 0) sred[wid] = v;
  __syncthreads();
  if (t == 0) sval = fmaxf(fmaxf(sred[0], sred[1]), fmaxf(sred[2], sred[3]));
  __syncthreads();
  float mx = sval;
  float e = (t < NSEG) ? expf(l - mx) : 0.f;
  v = e;
#pragma unroll
  for (int off = 32; off > 0; off >>= 1) v += __shfl_down(v, off, 64);
  if (lane == 0) sred[wid] = v;
  __syncthreads();
  if (t == 0) sval = sred[0] + sred[1] + sred[2] + sred[3];
  __syncthreads();
  float isum = 1.f / sval;
  if (t < NSEG) {
    float cn = counts[b * NSEG + t];
    float inv = cn > 0.f ? 1.f / cn : 0.f;
    att[t] = e * isum * inv;  // fold 1/count into attention weight
  }
  __syncthreads();

  const float* mb = sums + (size_t)b * NSEG * NC;
  {
    float s0 = 0.f, s1 = 0.f, s2 = 0.f, s3 = 0.f;
#pragma unroll 4
    for (int sg = 0; sg < NSEG; sg += 2) {
      float a0 = att[sg], a1 = att[sg + 1];
      const float* rp = mb + (size_t)sg * NC;
      s0 = fmaf(a0, rp[t], s0);
      s1 = fmaf(a0, rp[t + 256], s1);
      s2 = fmaf(a1, rp[NC + t], s2);
      s3 = fmaf(a1, rp[NC + t + 256], s3);
    }
    wm[t] = s0 + s2;
    wm[t + 256] = s1 + s3;
  }
  __syncthreads();

  if (t < 152) {
    int g = t / NCLS, cls = t - g * NCLS;
    float p = 0.f;
#pragma unroll 8
    for (int i = 0; i < 64; ++i) {
      int k = g + 8 * i;
      p = fmaf(wm[k], Wh[k * NCLS + cls], p);
    }
    part[g][cls] = p;
  }
  __syncthreads();
  if (t < NCLS) {
    float s = bh[t];
#pragma unroll
    for (int g = 0; g < 8; ++g) s += part[g][t];
    lg[t] = s;
    out[b * NCLS + t] = s;
  }
  __syncthreads();
  if (t < 64) {
    float term = 0.f;
    if (t < NCLS) {
      float xg = lg[t];
      term = fmaxf(xg, 0.f) - xg * target[b * NCLS + t] + log1pf(expf(-fabsf(xg)));
    }
#pragma unroll
    for (int off = 32; off > 0; off >>= 1) term += __shfl_down(term, off, 64);
    if (t == 0) wloss[b] = term;
  }
}

// ---------------------------------------------------------------------------
// K5: final loss reduce
// ---------------------------------------------------------------------------
__global__ void k_loss(const float* __restrict__ wloss, float* __restrict__ out) {
  int t = threadIdx.x;
  float v = (t < NB) ? wloss[t] : 0.f;
#pragma unroll
  for (int off = 32; off > 0; off >>= 1) v += __shfl_down(v, off, 64);
  if (t == 0) out[NB * NCLS] = v * (1.f / (NB * NCLS));
}

extern "C" void kernel_launch(void* const* d_in, const int* in_sizes, int n_in,
                              void* d_out, int out_size, void* d_ws, size_t ws_size,
                              hipStream_t stream) {
  const float* x = (const float*)d_in[0];
  const int* mask = (const int*)d_in[1];
  const float* target = (const float*)d_in[2];
  const float* Wa1 = (const float*)d_in[3];
  const float* ba1 = (const float*)d_in[4];
  const float* Wa2 = (const float*)d_in[5];
  const float* ba2 = (const float*)d_in[6];
  const float* Wh = (const float*)d_in[7];
  const float* bh = (const float*)d_in[8];
  float* out = (float*)d_out;

  char* ws = (char*)d_ws;
  float* sums = (float*)ws;
  float* counts = (float*)(ws + OFF_COUNTS);
  float* alog = (float*)(ws + OFF_ALOG);
  float* wloss = (float*)(ws + OFF_WLOSS);
  unsigned char* ids = (unsigned char*)(ws + OFF_IDS);

  k_zero<<<513, 256, 0, stream>>>((float4*)ws);
  k_ids_counts<<<dim3(4, NB), 256, 0, stream>>>(mask, ids, counts);
  k_segmeans<<<dim3(8, 4, NB), 256, 0, stream>>>(x, ids, sums);
  k_att<<<dim3(16, NB), 512, 0, stream>>>(sums, counts, Wa1, ba1, Wa2, ba2, alog);
  k_head<<<NB, 256, 0, stream>>>(sums, counts, alog, Wh, bh, target, out, wloss);
  k_loss<<<1, 64, 0, stream>>>(wloss, out);
}